// Round 2
// baseline (638.673 us; speedup 1.0000x reference)
//
#include <hip/hip_runtime.h>
#include <stdint.h>

// Problem constants (B=4, S=1536, D=2048, H=16, hd=128)
#define BB 4
#define SS 1536
#define DD 2048
#define HH 16
#define HD 128
#define BS (BB * SS)        // 6144 rows
#define N3 (3 * DD)         // 6144

typedef __bf16 bf16x8 __attribute__((ext_vector_type(8)));
typedef float f32x4 __attribute__((ext_vector_type(4)));

__device__ __forceinline__ void async16(const void* g, void* lds) {
  __builtin_amdgcn_global_load_lds(
      (const __attribute__((address_space(1))) unsigned int*)g,
      (__attribute__((address_space(3))) unsigned int*)lds, 16, 0, 0);
}

__global__ __launch_bounds__(256) void cast_bf16_kernel(
    const float* __restrict__ in, __bf16* __restrict__ out) {
  long i = ((long)blockIdx.x * 256 + threadIdx.x) * 8;
  float4 a = *(const float4*)(in + i);
  float4 b = *(const float4*)(in + i + 4);
  bf16x8 o;
  o[0] = (__bf16)a.x; o[1] = (__bf16)a.y; o[2] = (__bf16)a.z; o[3] = (__bf16)a.w;
  o[4] = (__bf16)b.x; o[5] = (__bf16)b.y; o[6] = (__bf16)b.z; o[7] = (__bf16)b.w;
  *(bf16x8*)(out + i) = o;
}

__global__ __launch_bounds__(256) void transpose_cast_kernel(
    const float* __restrict__ in, __bf16* __restrict__ out, int R, int C) {
  __shared__ __bf16 t[32][33];
  int tx = threadIdx.x & 31, ty = threadIdx.x >> 5;  // 32 x 8
  long r0 = (long)blockIdx.y * 32, c0 = (long)blockIdx.x * 32;
#pragma unroll
  for (int i = 0; i < 4; ++i)
    t[ty + i * 8][tx] = (__bf16)in[(r0 + ty + i * 8) * C + c0 + tx];
  __syncthreads();
#pragma unroll
  for (int i = 0; i < 4; ++i)
    out[(c0 + ty + i * 8) * R + r0 + tx] = t[tx][ty + i * 8];
}

__device__ __forceinline__ void store_val(__bf16* p, float v) { *p = (__bf16)v; }
__device__ __forceinline__ void store_val(float* p, float v) { *p = v; }

// ---------------------------------------------------------------------------
// 256x256 8-phase GEMM with ONE-PHASE-AHEAD ds_read pipelining.
// 512 thr / 8 waves (2m x 4n), BK=64, LDS 128 KiB, chunk-XOR swizzle.
// Quadrant order per K-tile: Q1(r0-3,c0-1) Q2(r0-3,c2-3) Q3(r4-7,c2-3)
// Q4(r4-7,c0-1) -> per-phase frags loadable one phase early in 24 frags:
//   R1{afL,bfL}(12)@ph8-post  R2{bfH}(4)@ph1-pre  R3{afH}(8)@ph2-pre
//   R5{afL',bfL'}(12)@ph4-post R6{bfH'}(4)@ph5-pre R7{afH'}(8)@ph6-pre
// Counted waits: ph1 lgkm(4), ph2 lgkm(8), ph3 lgkm(0), ph4 lgkm(0)=fence,
// mirrored for ph5-8. Stage: ph1 B1(t+1); ph4 A0A1B0(t+2)+vmcnt(6);
// ph5 B1(t+2); ph8 A0A1B0(t+3)+vmcnt(6). vmcnt(6) retires exactly the 8
// loads of the tile needed next; every LDS overwrite is after its victim's
// read-drain. sched_barrier(0) at every region boundary pins read counts.
// ---------------------------------------------------------------------------
#define PH_WAIT(N)                                              \
  __builtin_amdgcn_s_barrier();                                 \
  asm volatile("s_waitcnt lgkmcnt(" #N ")" ::: "memory");       \
  __builtin_amdgcn_sched_barrier(0);                            \
  __builtin_amdgcn_s_setprio(1)
#define PH_END()                                                \
  __builtin_amdgcn_s_setprio(0);                                \
  __builtin_amdgcn_s_barrier();                                 \
  __builtin_amdgcn_sched_barrier(0)
#define MFMA16(AF, BF, IOFF, JOFF)                                           \
  _Pragma("unroll") for (int i_ = 0; i_ < 4; ++i_)                           \
  _Pragma("unroll") for (int j_ = 0; j_ < 2; ++j_)                           \
  _Pragma("unroll") for (int kk_ = 0; kk_ < 2; ++kk_)                        \
    acc[(IOFF) + i_][(JOFF) + j_] = __builtin_amdgcn_mfma_f32_16x16x32_bf16( \
        AF[i_][kk_], BF[j_][kk_], acc[(IOFF) + i_][(JOFF) + j_], 0, 0, 0)

template <typename OutT>
__global__ __launch_bounds__(512, 2) void gemm256_kernel(
    const __bf16* __restrict__ A, const __bf16* __restrict__ Bt,
    const float* __restrict__ bias, OutT* __restrict__ C,
    int M, int N, int K) {
  __shared__ __attribute__((aligned(16))) __bf16 sA[2][2][128 * 64];  // 64 KB
  __shared__ __attribute__((aligned(16))) __bf16 sB[2][2][128 * 64];  // 64 KB

  const int tid = threadIdx.x;
  const int wave = tid >> 6, lane = tid & 63;
  const int quad = lane >> 4, l15 = lane & 15;
  const int s7 = l15 & 7;
  const int wm = wave >> 2, wn = wave & 3;

  // XCD-aware swizzle (nwg % 8 == 0 for both call sites)
  const int nwg = gridDim.x;
  int wg = (int)blockIdx.x;
  wg = (wg & 7) * (nwg >> 3) + (wg >> 3);
  const int NB = N >> 8;
  const int bm = (wg / NB) << 8;
  const int bn = (wg % NB) << 8;

  // staging source: row-in-half = wave*16 + t8*8 + srow, chunk pre-swizzled
  const int srow = lane >> 3;
  const int schunk = (lane & 7) ^ srow;
  const __bf16* Abase = A + (long)bm * K;
  const __bf16* Bbase = Bt + (long)bn * K;
  const int soff0 = (wave * 16 + 0 + srow) * K + schunk * 8;
  const int soff1 = (wave * 16 + 8 + srow) * K + schunk * 8;

  auto stageA = [&](int kt, int b, int h) {
    const __bf16* p = Abase + (long)h * 128 * K + kt * 64;
    async16(p + soff0, &sA[b][h][(wave * 16 + 0) * 64]);
    async16(p + soff1, &sA[b][h][(wave * 16 + 8) * 64]);
  };
  auto stageB = [&](int kt, int b, int h) {
    const __bf16* p = Bbase + (long)h * 128 * K + kt * 64;
    async16(p + soff0, &sB[b][h][(wave * 16 + 0) * 64]);
    async16(p + soff1, &sB[b][h][(wave * 16 + 8) * 64]);
  };
  auto readA = [&](int b, int i, int kk) -> bf16x8 {
    return *(const bf16x8*)&sA[b][wm]
        [(i * 16 + l15) * 64 + (((kk * 4 + quad) ^ s7) * 8)];
  };
  auto readB = [&](int b, int j, int kk) -> bf16x8 {
    return *(const bf16x8*)&sB[b][wn >> 1]
        [((wn & 1) * 64 + j * 16 + l15) * 64 + (((kk * 4 + quad) ^ s7) * 8)];
  };

  f32x4 acc[8][4] = {};
  bf16x8 af[4][2], ah[4][2], bl[2][2], bh[2][2];

  // prologue: tile0 full (8), tile1 A0,A1,B0 (6); land tile0; read R1.
  stageA(0, 0, 0); stageA(0, 0, 1); stageB(0, 0, 0); stageB(0, 0, 1);
  stageA(1, 1, 0); stageA(1, 1, 1); stageB(1, 1, 0);
  asm volatile("s_waitcnt vmcnt(6)" ::: "memory");
  __builtin_amdgcn_s_barrier();
  __builtin_amdgcn_sched_barrier(0);
#pragma unroll
  for (int i = 0; i < 4; ++i) { af[i][0] = readA(0, i, 0); af[i][1] = readA(0, i, 1); }
#pragma unroll
  for (int j = 0; j < 2; ++j) { bl[j][0] = readB(0, j, 0); bl[j][1] = readB(0, j, 1); }

  const int NT = K >> 6;  // K-tiles of 64

#pragma unroll 1
  for (int t = 0; t < NT; t += 2) {
    const bool full = (t + 2) < NT;

    // ---- ph1: acc[0..3][0..1] = af x bl (buf0) ----
#pragma unroll
    for (int j = 0; j < 2; ++j) { bh[j][0] = readB(0, 2 + j, 0); bh[j][1] = readB(0, 2 + j, 1); }  // R2
    stageB(t + 1, 1, 1);
    PH_WAIT(4);                    // drain R1, leave R2
    MFMA16(af, bl, 0, 0);
    PH_END();

    // ---- ph2: acc[0..3][2..3] = af x bh ----
#pragma unroll
    for (int i = 0; i < 4; ++i) { ah[i][0] = readA(0, 4 + i, 0); ah[i][1] = readA(0, 4 + i, 1); }  // R3
    PH_WAIT(8);                    // drain R2, leave R3
    MFMA16(af, bh, 0, 2);
    PH_END();

    // ---- ph3: acc[4..7][2..3] = ah x bh ----
    PH_WAIT(0);                    // drain R3
    MFMA16(ah, bh, 4, 2);
    PH_END();

    // ---- ph4: acc[4..7][0..1] = ah x bl; stage t+2 A0,A1,B0; R5 after MFMA ----
    if (full) {
      stageA(t + 2, 0, 0); stageA(t + 2, 0, 1); stageB(t + 2, 0, 0);
      asm volatile("s_waitcnt vmcnt(6)" ::: "memory");   // tile t+1 landed
    } else {
      asm volatile("s_waitcnt vmcnt(0)" ::: "memory");
    }
    PH_WAIT(0);                    // nothing outstanding; fence only
    MFMA16(ah, bl, 4, 0);
#pragma unroll
    for (int i = 0; i < 4; ++i) { af[i][0] = readA(1, i, 0); af[i][1] = readA(1, i, 1); }  // R5
#pragma unroll
    for (int j = 0; j < 2; ++j) { bl[j][0] = readB(1, j, 0); bl[j][1] = readB(1, j, 1); }
    PH_END();

    // ---- ph5: acc[0..3][0..1] = af x bl (buf1) ----
#pragma unroll
    for (int j = 0; j < 2; ++j) { bh[j][0] = readB(1, 2 + j, 0); bh[j][1] = readB(1, 2 + j, 1); }  // R6
    if (full) stageB(t + 2, 0, 1);
    PH_WAIT(4);                    // drain R5, leave R6
    MFMA16(af, bl, 0, 0);
    PH_END();

    // ---- ph6: acc[0..3][2..3] = af x bh ----
#pragma unroll
    for (int i = 0; i < 4; ++i) { ah[i][0] = readA(1, 4 + i, 0); ah[i][1] = readA(1, 4 + i, 1); }  // R7
    PH_WAIT(8);                    // drain R6, leave R7
    MFMA16(af, bh, 0, 2);
    PH_END();

    // ---- ph7: acc[4..7][2..3] = ah x bh ----
    PH_WAIT(0);                    // drain R7
    MFMA16(ah, bh, 4, 2);
    PH_END();

    // ---- ph8: acc[4..7][0..1] = ah x bl; stage t+3; R1' after MFMA ----
    if (full) {
      stageA(t + 3, 1, 0); stageA(t + 3, 1, 1); stageB(t + 3, 1, 0);
      asm volatile("s_waitcnt vmcnt(6)" ::: "memory");   // tile t+2 landed
    } else {
      asm volatile("s_waitcnt vmcnt(0)" ::: "memory");
    }
    PH_WAIT(0);                    // fence only
    MFMA16(ah, bl, 4, 0);
    if (full) {
#pragma unroll
      for (int i = 0; i < 4; ++i) { af[i][0] = readA(0, i, 0); af[i][1] = readA(0, i, 1); }  // R1'
#pragma unroll
      for (int j = 0; j < 2; ++j) { bl[j][0] = readB(0, j, 0); bl[j][1] = readB(0, j, 1); }
    }
    PH_END();
  }

  // epilogue
#pragma unroll
  for (int i = 0; i < 8; ++i) {
    int row0 = bm + wm * 128 + i * 16 + quad * 4;
#pragma unroll
    for (int j = 0; j < 4; ++j) {
      int col = bn + wn * 64 + j * 16 + l15;
      float bv = bias[col];
#pragma unroll
      for (int r = 0; r < 4; ++r)
        store_val(&C[(long)(row0 + r) * N + col], acc[i][j][r] + bv);
    }
  }
}

__global__ __launch_bounds__(256) void rmsnorm_kernel(
    __bf16* __restrict__ qkv, const float* __restrict__ qw,
    const float* __restrict__ kw) {
  const int r = blockIdx.x;
  const bool isQ = r < BS;
  const int row = isQ ? r : r - BS;
  __bf16* p = qkv + (long)row * N3 + (isQ ? 0 : DD);
  const float* w = isQ ? qw : kw;
  const float extra = isQ ? (0.0883883476483184f * 1.44269504088896f) : 1.0f;
  const int t = threadIdx.x;

  bf16x8 v = *(const bf16x8*)(p + t * 8);
  float f[8];
  float s = 0.f;
#pragma unroll
  for (int i = 0; i < 8; ++i) { f[i] = (float)v[i]; s += f[i] * f[i]; }
#pragma unroll
  for (int off = 32; off > 0; off >>= 1) s += __shfl_xor(s, off, 64);
  __shared__ float red[4];
  if ((t & 63) == 0) red[t >> 6] = s;
  __syncthreads();
  float tot = red[0] + red[1] + red[2] + red[3];
  float rs = rsqrtf(tot * (1.0f / (float)DD) + 1e-6f) * extra;
  bf16x8 o;
#pragma unroll
  for (int i = 0; i < 8; ++i) o[i] = (__bf16)(f[i] * rs * w[t * 8 + i]);
  *(bf16x8*)(p + t * 8) = o;
}

__global__ __launch_bounds__(256) void transpose_v_kernel(
    const __bf16* __restrict__ qkv, __bf16* __restrict__ vt) {
  __shared__ __bf16 t[32][33];
  const int bh = blockIdx.z, b = bh >> 4, h = bh & 15;
  const int s0 = blockIdx.x * 32, d0 = blockIdx.y * 32;
  const int tx = threadIdx.x & 31, ty = threadIdx.x >> 5;
#pragma unroll
  for (int i = 0; i < 4; ++i) {
    int s = s0 + ty + i * 8;
    t[ty + i * 8][tx] =
        qkv[(long)(b * SS + s) * N3 + 2 * DD + h * HD + d0 + tx];
  }
  __syncthreads();
#pragma unroll
  for (int i = 0; i < 4; ++i) {
    int d = d0 + ty + i * 8;
    vt[((long)bh * HD + d) * SS + s0 + tx] = t[tx][ty + i * 8];
  }
}

// ---------------------------------------------------------------------------
// Flash attention v5, causal. grid (S/128, B*H), 4 waves; wave owns 32 q-rows.
// (unchanged this round — GEMM pipelining is the experiment)
// ---------------------------------------------------------------------------
__global__ __launch_bounds__(256, 2) void attn_kernel(
    const __bf16* __restrict__ qkv, const __bf16* __restrict__ vt,
    __bf16* __restrict__ O) {
  __shared__ __attribute__((aligned(16))) __bf16 sK[2][64 * 128];  // 32 KB
  __shared__ __attribute__((aligned(16))) __bf16 sV[2][128 * 64];  // 32 KB
  __shared__ __attribute__((aligned(16))) __bf16 sP[4][32 * 64];   // 16 KB

  const int qi = gridDim.x - 1 - blockIdx.x, bh = blockIdx.y;
  const int b = bh >> 4, h = bh & 15;
  const int tid = threadIdx.x, wave = tid >> 6, lane = tid & 63;
  const int quad = lane >> 4, l15 = lane & 15;
  const int sw3 = l15 & 7;

  const long rowQ0 = (long)(b * SS + qi * 128);   // block's first q row
  const int qrow0 = qi * 128 + wave * 32;         // wave's first q row (in S)
  const __bf16* kbase = qkv + (long)(b * SS) * N3 + DD + h * HD;
  const __bf16* vbase = vt + (long)bh * HD * SS;

  // Q fragments in registers: qf[mt][kk] for row-tile mt (rows +mt*16)
  bf16x8 qf[2][4];
#pragma unroll
  for (int mt = 0; mt < 2; ++mt) {
    const __bf16* qp =
        qkv + (rowQ0 + wave * 32 + mt * 16 + l15) * N3 + h * HD + quad * 8;
#pragma unroll
    for (int kk = 0; kk < 4; ++kk) qf[mt][kk] = *(const bf16x8*)(qp + kk * 32);
  }

  f32x4 o_acc[2][8] = {};
  float l_acc[2][4] = {};

  __bf16* sPw = &sP[wave][0];
  const int jn = 2 * qi + 2;  // K tiles 0 .. 2qi+1 (block-uniform)

  // ---- staging helper (wave-uniform LDS dst bases) ----
  auto stageKV = [&](int j, int buf) {
#pragma unroll
    for (int t = 0; t < 4; ++t) {  // K tile 64x128: inst covers 4 rows
      int rbase = wave * 16 + t * 4;            // wave-uniform
      int row = rbase + quad;
      const __bf16* src =
          kbase + (long)(j * 64 + row) * N3 + ((l15 ^ (row & 7)) * 8);
      async16(src, &sK[buf][rbase * 128]);
    }
#pragma unroll
    for (int t = 0; t < 4; ++t) {  // V^T tile 128x64: inst covers 8 rows
      int rbase = wave * 32 + t * 8;            // wave-uniform
      int row = rbase + (lane >> 3);
      const __bf16* src = vbase + (long)row * SS + j * 64 +
                          (((lane & 7) ^ (row & 7)) * 8);
      async16(src, &sV[buf][rbase * 64]);
    }
  };

  stageKV(0, 0);

  for (int j = 0; j < jn; ++j) {
    const int buf = j & 1;
    __syncthreads();                 // waits stage(j) (+ prev compute done)
    if (j + 1 < jn) stageKV(j + 1, buf ^ 1);  // prefetch, hidden by compute(j)

    // wave 0/1 rows are entirely above the diagonal for the final K tile
    const bool active = !((j == 2 * qi + 1) && (wave < 2));
    if (active) {
      const bool needMask =
          ((j == 2 * qi) && (wave < 2)) || ((j == 2 * qi + 1) && (wave >= 2));

      // ---- S = Q K^T : 16 bk reads feed 32 MFMAs ----
      f32x4 sacc[2][4];
#pragma unroll
      for (int nt = 0; nt < 4; ++nt) {
        sacc[0][nt] = (f32x4){0.f, 0.f, 0.f, 0.f};
        sacc[1][nt] = (f32x4){0.f, 0.f, 0.f, 0.f};
#pragma unroll
        for (int kk = 0; kk < 4; ++kk) {
          bf16x8 bk = *(const bf16x8*)
              &sK[buf][(nt * 16 + l15) * 128 + (((kk * 4 + quad) ^ sw3) * 8)];
          sacc[0][nt] = __builtin_amdgcn_mfma_f32_16x16x32_bf16(
              qf[0][kk], bk, sacc[0][nt], 0, 0, 0);
          sacc[1][nt] = __builtin_amdgcn_mfma_f32_16x16x32_bf16(
              qf[1][kk], bk, sacc[1][nt], 0, 0, 0);
        }
      }
      if (needMask) {
#pragma unroll
        for (int mt = 0; mt < 2; ++mt) {
          int rowg0 = qrow0 + mt * 16 + quad * 4;
#pragma unroll
          for (int nt = 0; nt < 4; ++nt) {
            int colg = j * 64 + nt * 16 + l15;
#pragma unroll
            for (int r = 0; r < 4; ++r)
              if (colg > rowg0 + r) sacc[mt][nt][r] = -1e30f;
          }
        }
      }
      // ---- p = exp2(s) -> sP (wave-private), accumulate l per lane ----
#pragma unroll
      for (int mt = 0; mt < 2; ++mt) {
#pragma unroll
        for (int nt = 0; nt < 4; ++nt) {
#pragma unroll
          for (int r = 0; r < 4; ++r) {
            float pv = exp2f(sacc[mt][nt][r]);
            l_acc[mt][r] += pv;
            int prow = mt * 16 + quad * 4 + r;
            int pcol = nt * 16 + l15;
            sPw[prow * 64 + (((pcol >> 3) ^ (prow & 7)) * 8) + (pcol & 7)] =
                (__bf16)pv;
          }
        }
      }
      // ---- O += P V : 4 ap + 16 bv reads feed 32 MFMAs ----
#pragma unroll
      for (int kk = 0; kk < 2; ++kk) {
        bf16x8 ap0 = *(const bf16x8*)
            &sPw[l15 * 64 + (((kk * 4 + quad) ^ sw3) * 8)];
        bf16x8 ap1 = *(const bf16x8*)
            &sPw[(16 + l15) * 64 + (((kk * 4 + quad) ^ sw3) * 8)];
#pragma unroll
        for (int dt = 0; dt < 8; ++dt) {
          bf16x8 bv = *(const bf16x8*)
              &sV[buf][(dt * 16 + l15) * 64 + (((kk * 4 + quad) ^ sw3) * 8)];
          o_acc[0][dt] = __builtin_amdgcn_mfma_f32_16x16x32_bf16(
              ap0, bv, o_acc[0][dt], 0, 0, 0);
          o_acc[1][dt] = __builtin_amdgcn_mfma_f32_16x16x32_bf16(
              ap1, bv, o_acc[1][dt], 0, 0, 0);
        }
      }
    }
  }

  // final l reduction across the 16 lanes of each quad-row, then write O
#pragma unroll
  for (int mt = 0; mt < 2; ++mt) {
    __bf16* obase = O + (rowQ0 + wave * 32 + mt * 16 + quad * 4) * DD + h * HD;
#pragma unroll
    for (int r = 0; r < 4; ++r) {
      float l = l_acc[mt][r];
#pragma unroll
      for (int off = 1; off < 16; off <<= 1) l += __shfl_xor(l, off, 64);
      float inv = 1.0f / l;
#pragma unroll
      for (int dt = 0; dt < 8; ++dt)
        obase[(long)r * DD + dt * 16 + l15] = (__bf16)(o_acc[mt][dt][r] * inv);
    }
  }
}

extern "C" void kernel_launch(void* const* d_in, const int* in_sizes, int n_in,
                              void* d_out, int out_size, void* d_ws,
                              size_t ws_size, hipStream_t stream) {
  const float* x      = (const float*)d_in[0];
  const float* w_qkv  = (const float*)d_in[1];
  const float* b_qkv  = (const float*)d_in[2];
  const float* q_ln_w = (const float*)d_in[3];
  const float* k_ln_w = (const float*)d_in[4];
  const float* w_out  = (const float*)d_in[5];
  const float* b_out  = (const float*)d_in[6];
  float* out = (float*)d_out;

  char* w = (char*)d_ws;
  __bf16* xb    = (__bf16*)(w);
  __bf16* wqkvT = (__bf16*)(w + 25165824L);
  __bf16* woutT = (__bf16*)(w + 50331648L);
  __bf16* qkvb  = (__bf16*)(w + 58720256L);
  __bf16* vtb   = (__bf16*)(w + 134217728L);
  __bf16* atto  = xb;

  cast_bf16_kernel<<<dim3(BS * DD / 2048), 256, 0, stream>>>(x, xb);
  transpose_cast_kernel<<<dim3(N3 / 32, DD / 32), 256, 0, stream>>>(
      w_qkv, wqkvT, DD, N3);
  transpose_cast_kernel<<<dim3(DD / 32, DD / 32), 256, 0, stream>>>(
      w_out, woutT, DD, DD);

  gemm256_kernel<__bf16><<<dim3((BS / 256) * (N3 / 256)), 512, 0, stream>>>(
      xb, wqkvT, b_qkv, qkvb, BS, N3, DD);

  rmsnorm_kernel<<<dim3(2 * BS), 256, 0, stream>>>(qkvb, q_ln_w, k_ln_w);

  transpose_v_kernel<<<dim3(SS / 32, HD / 32, BB * HH), 256, 0, stream>>>(
      qkvb, vtb);

  attn_kernel<<<dim3(SS / 128, BB * HH), 256, 0, stream>>>(qkvb, vtb, atto);

  gemm256_kernel<float><<<dim3((BS / 256) * (DD / 256)), 512, 0, stream>>>(
      atto, woutT, b_out, out, BS, DD, DD);
}

// Round 3
// 545.765 us; speedup vs baseline: 1.1702x; 1.1702x over previous
//
#include <hip/hip_runtime.h>
#include <stdint.h>

// Problem constants (B=4, S=1536, D=2048, H=16, hd=128)
#define BB 4
#define SS 1536
#define DD 2048
#define HH 16
#define HD 128
#define BS (BB * SS)        // 6144 rows
#define N3 (3 * DD)         // 6144

typedef __bf16 bf16x8 __attribute__((ext_vector_type(8)));
typedef float f32x4 __attribute__((ext_vector_type(4)));

__device__ __forceinline__ void async16(const void* g, void* lds) {
  __builtin_amdgcn_global_load_lds(
      (const __attribute__((address_space(1))) unsigned int*)g,
      (__attribute__((address_space(3))) unsigned int*)lds, 16, 0, 0);
}

__global__ __launch_bounds__(256) void cast_bf16_kernel(
    const float* __restrict__ in, __bf16* __restrict__ out) {
  long i = ((long)blockIdx.x * 256 + threadIdx.x) * 8;
  float4 a = *(const float4*)(in + i);
  float4 b = *(const float4*)(in + i + 4);
  bf16x8 o;
  o[0] = (__bf16)a.x; o[1] = (__bf16)a.y; o[2] = (__bf16)a.z; o[3] = (__bf16)a.w;
  o[4] = (__bf16)b.x; o[5] = (__bf16)b.y; o[6] = (__bf16)b.z; o[7] = (__bf16)b.w;
  *(bf16x8*)(out + i) = o;
}

__global__ __launch_bounds__(256) void transpose_cast_kernel(
    const float* __restrict__ in, __bf16* __restrict__ out, int R, int C) {
  __shared__ __bf16 t[32][33];
  int tx = threadIdx.x & 31, ty = threadIdx.x >> 5;  // 32 x 8
  long r0 = (long)blockIdx.y * 32, c0 = (long)blockIdx.x * 32;
#pragma unroll
  for (int i = 0; i < 4; ++i)
    t[ty + i * 8][tx] = (__bf16)in[(r0 + ty + i * 8) * C + c0 + tx];
  __syncthreads();
#pragma unroll
  for (int i = 0; i < 4; ++i)
    out[(c0 + ty + i * 8) * R + r0 + tx] = t[tx][ty + i * 8];
}

// ---------------------------------------------------------------------------
// GEMM with XOR-swizzled LDS (chunk c of row r at slot c ^ ((r>>1)&3)).
// Round-0 proven version: 128x128 tile, 2304 blocks (exactly 3 rounds on
// 256 CUs at 3 blocks/CU), 761 TF, no spills, 0 bank conflicts.
// ---------------------------------------------------------------------------
__device__ __forceinline__ void store_val(__bf16* p, float v) { *p = (__bf16)v; }
__device__ __forceinline__ void store_val(float* p, float v) { *p = v; }

template <typename OutT>
__global__ __launch_bounds__(256, 2) void gemm_bt_kernel(
    const __bf16* __restrict__ A, const __bf16* __restrict__ Bt,
    const float* __restrict__ bias, OutT* __restrict__ C,
    int M, int N, int K) {
  __shared__ __attribute__((aligned(16))) __bf16 sA[128 * 32];
  __shared__ __attribute__((aligned(16))) __bf16 sB[128 * 32];
  const int tid = threadIdx.x;
  const int wave = tid >> 6, lane = tid & 63;
  const int quad = lane >> 4, l15 = lane & 15;
  const int bm = blockIdx.y * 128, bn = blockIdx.x * 128;
  const int wr = (wave >> 1) * 64, wc = (wave & 1) * 64;

  const int srow = lane >> 2;
  const int scol = ((lane & 3) ^ ((lane >> 3) & 3)) * 8;  // swizzled source
  const __bf16* Ap = A + (long)(bm + wave * 32 + srow) * K + scol;
  const __bf16* Bp = Bt + (long)(bn + wave * 32 + srow) * K + scol;
  __bf16* sAw = &sA[wave * 32 * 32];
  __bf16* sBw = &sB[wave * 32 * 32];

  const int achunk = (quad ^ ((l15 >> 1) & 3)) * 8;  // swizzled frag read

  f32x4 acc[4][4] = {};

  for (int k0 = 0; k0 < K; k0 += 32) {
    __syncthreads();
    async16(Ap + k0, sAw);
    async16(Ap + k0 + (long)16 * K, sAw + 16 * 32);
    async16(Bp + k0, sBw);
    async16(Bp + k0 + (long)16 * K, sBw + 16 * 32);
    __syncthreads();
    bf16x8 af[4], bfr[4];
#pragma unroll
    for (int i = 0; i < 4; ++i)
      af[i] = *(const bf16x8*)&sA[(wr + i * 16 + l15) * 32 + achunk];
#pragma unroll
    for (int i = 0; i < 4; ++i)
      bfr[i] = *(const bf16x8*)&sB[(wc + i * 16 + l15) * 32 + achunk];
#pragma unroll
    for (int i = 0; i < 4; ++i)
#pragma unroll
      for (int j = 0; j < 4; ++j)
        acc[i][j] = __builtin_amdgcn_mfma_f32_16x16x32_bf16(af[i], bfr[j],
                                                            acc[i][j], 0, 0, 0);
  }

#pragma unroll
  for (int i = 0; i < 4; ++i) {
    int row0 = bm + wr + i * 16 + quad * 4;
#pragma unroll
    for (int j = 0; j < 4; ++j) {
      int col = bn + wc + j * 16 + l15;
      float bv = bias[col];
#pragma unroll
      for (int r = 0; r < 4; ++r)
        store_val(&C[(long)(row0 + r) * N + col], acc[i][j][r] + bv);
    }
  }
}

__global__ __launch_bounds__(256) void rmsnorm_kernel(
    __bf16* __restrict__ qkv, const float* __restrict__ qw,
    const float* __restrict__ kw) {
  const int r = blockIdx.x;
  const bool isQ = r < BS;
  const int row = isQ ? r : r - BS;
  __bf16* p = qkv + (long)row * N3 + (isQ ? 0 : DD);
  const float* w = isQ ? qw : kw;
  const float extra = isQ ? (0.0883883476483184f * 1.44269504088896f) : 1.0f;
  const int t = threadIdx.x;

  bf16x8 v = *(const bf16x8*)(p + t * 8);
  float f[8];
  float s = 0.f;
#pragma unroll
  for (int i = 0; i < 8; ++i) { f[i] = (float)v[i]; s += f[i] * f[i]; }
#pragma unroll
  for (int off = 32; off > 0; off >>= 1) s += __shfl_xor(s, off, 64);
  __shared__ float red[4];
  if ((t & 63) == 0) red[t >> 6] = s;
  __syncthreads();
  float tot = red[0] + red[1] + red[2] + red[3];
  float rs = rsqrtf(tot * (1.0f / (float)DD) + 1e-6f) * extra;
  const float4 w0 = *(const float4*)(w + t * 8);
  const float4 w1 = *(const float4*)(w + t * 8 + 4);
  bf16x8 o;
  o[0] = (__bf16)(f[0] * rs * w0.x); o[1] = (__bf16)(f[1] * rs * w0.y);
  o[2] = (__bf16)(f[2] * rs * w0.z); o[3] = (__bf16)(f[3] * rs * w0.w);
  o[4] = (__bf16)(f[4] * rs * w1.x); o[5] = (__bf16)(f[5] * rs * w1.y);
  o[6] = (__bf16)(f[6] * rs * w1.z); o[7] = (__bf16)(f[7] * rs * w1.w);
  *(bf16x8*)(p + t * 8) = o;
}

__global__ __launch_bounds__(256) void transpose_v_kernel(
    const __bf16* __restrict__ qkv, __bf16* __restrict__ vt) {
  __shared__ __bf16 t[32][33];
  const int bh = blockIdx.z, b = bh >> 4, h = bh & 15;
  const int s0 = blockIdx.x * 32, d0 = blockIdx.y * 32;
  const int tx = threadIdx.x & 31, ty = threadIdx.x >> 5;
#pragma unroll
  for (int i = 0; i < 4; ++i) {
    int s = s0 + ty + i * 8;
    t[ty + i * 8][tx] =
        qkv[(long)(b * SS + s) * N3 + 2 * DD + h * HD + d0 + tx];
  }
  __syncthreads();
#pragma unroll
  for (int i = 0; i < 4; ++i) {
    int d = d0 + ty + i * 8;
    vt[((long)bh * HD + d) * SS + s0 + tx] = t[tx][ty + i * 8];
  }
}

// ---------------------------------------------------------------------------
// Flash attention v5, causal. grid (S/128, B*H), 4 waves; wave owns 32 q-rows.
// This round: + setprio(1) around MFMA clusters (T5; attn is the regime where
// it pays: 2 independent blocks/CU at different phases), + QK loop reordered
// kk-outer so dependent MFMAs on the same sacc are 8 apart instead of 2.
// ---------------------------------------------------------------------------
__global__ __launch_bounds__(256, 2) void attn_kernel(
    const __bf16* __restrict__ qkv, const __bf16* __restrict__ vt,
    __bf16* __restrict__ O) {
  __shared__ __attribute__((aligned(16))) __bf16 sK[2][64 * 128];  // 32 KB
  __shared__ __attribute__((aligned(16))) __bf16 sV[2][128 * 64];  // 32 KB
  __shared__ __attribute__((aligned(16))) __bf16 sP[4][32 * 64];   // 16 KB

  const int qi = gridDim.x - 1 - blockIdx.x, bh = blockIdx.y;
  const int b = bh >> 4, h = bh & 15;
  const int tid = threadIdx.x, wave = tid >> 6, lane = tid & 63;
  const int quad = lane >> 4, l15 = lane & 15;
  const int sw3 = l15 & 7;

  const long rowQ0 = (long)(b * SS + qi * 128);   // block's first q row
  const int qrow0 = qi * 128 + wave * 32;         // wave's first q row (in S)
  const __bf16* kbase = qkv + (long)(b * SS) * N3 + DD + h * HD;
  const __bf16* vbase = vt + (long)bh * HD * SS;

  // Q fragments in registers: qf[mt][kk] for row-tile mt (rows +mt*16)
  bf16x8 qf[2][4];
#pragma unroll
  for (int mt = 0; mt < 2; ++mt) {
    const __bf16* qp =
        qkv + (rowQ0 + wave * 32 + mt * 16 + l15) * N3 + h * HD + quad * 8;
#pragma unroll
    for (int kk = 0; kk < 4; ++kk) qf[mt][kk] = *(const bf16x8*)(qp + kk * 32);
  }

  f32x4 o_acc[2][8] = {};
  float l_acc[2][4] = {};

  __bf16* sPw = &sP[wave][0];
  const int jn = 2 * qi + 2;  // K tiles 0 .. 2qi+1 (block-uniform)

  // ---- staging helper (wave-uniform LDS dst bases) ----
  auto stageKV = [&](int j, int buf) {
#pragma unroll
    for (int t = 0; t < 4; ++t) {  // K tile 64x128: inst covers 4 rows
      int rbase = wave * 16 + t * 4;            // wave-uniform
      int row = rbase + quad;
      const __bf16* src =
          kbase + (long)(j * 64 + row) * N3 + ((l15 ^ (row & 7)) * 8);
      async16(src, &sK[buf][rbase * 128]);
    }
#pragma unroll
    for (int t = 0; t < 4; ++t) {  // V^T tile 128x64: inst covers 8 rows
      int rbase = wave * 32 + t * 8;            // wave-uniform
      int row = rbase + (lane >> 3);
      const __bf16* src = vbase + (long)row * SS + j * 64 +
                          (((lane & 7) ^ (row & 7)) * 8);
      async16(src, &sV[buf][rbase * 64]);
    }
  };

  stageKV(0, 0);

  for (int j = 0; j < jn; ++j) {
    const int buf = j & 1;
    __syncthreads();                 // waits stage(j) (+ prev compute done)
    if (j + 1 < jn) stageKV(j + 1, buf ^ 1);  // prefetch, hidden by compute(j)

    // wave 0/1 rows are entirely above the diagonal for the final K tile
    const bool active = !((j == 2 * qi + 1) && (wave < 2));
    if (active) {
      const bool needMask =
          ((j == 2 * qi) && (wave < 2)) || ((j == 2 * qi + 1) && (wave >= 2));

      // ---- S = Q K^T : 16 bk reads feed 32 MFMAs (kk-outer: deps 8 apart) ----
      f32x4 sacc[2][4];
#pragma unroll
      for (int mt = 0; mt < 2; ++mt)
#pragma unroll
        for (int nt = 0; nt < 4; ++nt)
          sacc[mt][nt] = (f32x4){0.f, 0.f, 0.f, 0.f};
      __builtin_amdgcn_s_setprio(1);
#pragma unroll
      for (int kk = 0; kk < 4; ++kk) {
#pragma unroll
        for (int nt = 0; nt < 4; ++nt) {
          bf16x8 bk = *(const bf16x8*)
              &sK[buf][(nt * 16 + l15) * 128 + (((kk * 4 + quad) ^ sw3) * 8)];
          sacc[0][nt] = __builtin_amdgcn_mfma_f32_16x16x32_bf16(
              qf[0][kk], bk, sacc[0][nt], 0, 0, 0);
          sacc[1][nt] = __builtin_amdgcn_mfma_f32_16x16x32_bf16(
              qf[1][kk], bk, sacc[1][nt], 0, 0, 0);
        }
      }
      __builtin_amdgcn_s_setprio(0);
      if (needMask) {
#pragma unroll
        for (int mt = 0; mt < 2; ++mt) {
          int rowg0 = qrow0 + mt * 16 + quad * 4;
#pragma unroll
          for (int nt = 0; nt < 4; ++nt) {
            int colg = j * 64 + nt * 16 + l15;
#pragma unroll
            for (int r = 0; r < 4; ++r)
              if (colg > rowg0 + r) sacc[mt][nt][r] = -1e30f;
          }
        }
      }
      // ---- p = exp2(s) -> sP (wave-private), accumulate l per lane ----
#pragma unroll
      for (int mt = 0; mt < 2; ++mt) {
#pragma unroll
        for (int nt = 0; nt < 4; ++nt) {
#pragma unroll
          for (int r = 0; r < 4; ++r) {
            float pv = exp2f(sacc[mt][nt][r]);
            l_acc[mt][r] += pv;
            int prow = mt * 16 + quad * 4 + r;
            int pcol = nt * 16 + l15;
            sPw[prow * 64 + (((pcol >> 3) ^ (prow & 7)) * 8) + (pcol & 7)] =
                (__bf16)pv;
          }
        }
      }
      // ---- O += P V : 4 ap + 16 bv reads feed 32 MFMAs (deps 16 apart) ----
      __builtin_amdgcn_s_setprio(1);
#pragma unroll
      for (int kk = 0; kk < 2; ++kk) {
        bf16x8 ap0 = *(const bf16x8*)
            &sPw[l15 * 64 + (((kk * 4 + quad) ^ sw3) * 8)];
        bf16x8 ap1 = *(const bf16x8*)
            &sPw[(16 + l15) * 64 + (((kk * 4 + quad) ^ sw3) * 8)];
#pragma unroll
        for (int dt = 0; dt < 8; ++dt) {
          bf16x8 bv = *(const bf16x8*)
              &sV[buf][(dt * 16 + l15) * 64 + (((kk * 4 + quad) ^ sw3) * 8)];
          o_acc[0][dt] = __builtin_amdgcn_mfma_f32_16x16x32_bf16(
              ap0, bv, o_acc[0][dt], 0, 0, 0);
          o_acc[1][dt] = __builtin_amdgcn_mfma_f32_16x16x32_bf16(
              ap1, bv, o_acc[1][dt], 0, 0, 0);
        }
      }
      __builtin_amdgcn_s_setprio(0);
    }
  }

  // final l reduction across the 16 lanes of each quad-row, then write O
#pragma unroll
  for (int mt = 0; mt < 2; ++mt) {
    __bf16* obase = O + (rowQ0 + wave * 32 + mt * 16 + quad * 4) * DD + h * HD;
#pragma unroll
    for (int r = 0; r < 4; ++r) {
      float l = l_acc[mt][r];
#pragma unroll
      for (int off = 1; off < 16; off <<= 1) l += __shfl_xor(l, off, 64);
      float inv = 1.0f / l;
#pragma unroll
      for (int dt = 0; dt < 8; ++dt)
        obase[(long)r * DD + dt * 16 + l15] = (__bf16)(o_acc[mt][dt][r] * inv);
    }
  }
}

extern "C" void kernel_launch(void* const* d_in, const int* in_sizes, int n_in,
                              void* d_out, int out_size, void* d_ws,
                              size_t ws_size, hipStream_t stream) {
  const float* x      = (const float*)d_in[0];
  const float* w_qkv  = (const float*)d_in[1];
  const float* b_qkv  = (const float*)d_in[2];
  const float* q_ln_w = (const float*)d_in[3];
  const float* k_ln_w = (const float*)d_in[4];
  const float* w_out  = (const float*)d_in[5];
  const float* b_out  = (const float*)d_in[6];
  float* out = (float*)d_out;

  char* w = (char*)d_ws;
  __bf16* xb    = (__bf16*)(w);
  __bf16* wqkvT = (__bf16*)(w + 25165824L);
  __bf16* woutT = (__bf16*)(w + 50331648L);
  __bf16* qkvb  = (__bf16*)(w + 58720256L);
  __bf16* vtb   = (__bf16*)(w + 134217728L);
  __bf16* atto  = xb;

  cast_bf16_kernel<<<dim3(BS * DD / 2048), 256, 0, stream>>>(x, xb);
  transpose_cast_kernel<<<dim3(N3 / 32, DD / 32), 256, 0, stream>>>(
      w_qkv, wqkvT, DD, N3);
  transpose_cast_kernel<<<dim3(DD / 32, DD / 32), 256, 0, stream>>>(
      w_out, woutT, DD, DD);

  gemm_bt_kernel<__bf16><<<dim3(N3 / 128, BS / 128), 256, 0, stream>>>(
      xb, wqkvT, b_qkv, qkvb, BS, N3, DD);

  rmsnorm_kernel<<<dim3(2 * BS), 256, 0, stream>>>(qkvb, q_ln_w, k_ln_w);

  transpose_v_kernel<<<dim3(SS / 32, HD / 32, BB * HH), 256, 0, stream>>>(
      qkvb, vtb);

  attn_kernel<<<dim3(SS / 128, BB * HH), 256, 0, stream>>>(qkvb, vtb, atto);

  gemm_bt_kernel<float><<<dim3(DD / 128, BS / 128), 256, 0, stream>>>(
      atto, woutT, b_out, out, BS, DD, DD);
}

// Round 4
// 538.584 us; speedup vs baseline: 1.1858x; 1.0133x over previous
//
#include <hip/hip_runtime.h>
#include <stdint.h>

// Problem constants (B=4, S=1536, D=2048, H=16, hd=128)
#define BB 4
#define SS 1536
#define DD 2048
#define HH 16
#define HD 128
#define BS (BB * SS)        // 6144 rows
#define N3 (3 * DD)         // 6144

typedef __bf16 bf16x8 __attribute__((ext_vector_type(8)));
typedef float f32x4 __attribute__((ext_vector_type(4)));

__device__ __forceinline__ void async16(const void* g, void* lds) {
  __builtin_amdgcn_global_load_lds(
      (const __attribute__((address_space(1))) unsigned int*)g,
      (__attribute__((address_space(3))) unsigned int*)lds, 16, 0, 0);
}

__global__ __launch_bounds__(256) void cast_bf16_kernel(
    const float* __restrict__ in, __bf16* __restrict__ out) {
  long i = ((long)blockIdx.x * 256 + threadIdx.x) * 8;
  float4 a = *(const float4*)(in + i);
  float4 b = *(const float4*)(in + i + 4);
  bf16x8 o;
  o[0] = (__bf16)a.x; o[1] = (__bf16)a.y; o[2] = (__bf16)a.z; o[3] = (__bf16)a.w;
  o[4] = (__bf16)b.x; o[5] = (__bf16)b.y; o[6] = (__bf16)b.z; o[7] = (__bf16)b.w;
  *(bf16x8*)(out + i) = o;
}

__global__ __launch_bounds__(256) void transpose_cast_kernel(
    const float* __restrict__ in, __bf16* __restrict__ out, int R, int C) {
  __shared__ __bf16 t[32][33];
  int tx = threadIdx.x & 31, ty = threadIdx.x >> 5;  // 32 x 8
  long r0 = (long)blockIdx.y * 32, c0 = (long)blockIdx.x * 32;
#pragma unroll
  for (int i = 0; i < 4; ++i)
    t[ty + i * 8][tx] = (__bf16)in[(r0 + ty + i * 8) * C + c0 + tx];
  __syncthreads();
#pragma unroll
  for (int i = 0; i < 4; ++i)
    out[(c0 + ty + i * 8) * R + r0 + tx] = t[tx][ty + i * 8];
}

// ---------------------------------------------------------------------------
// GEMM with XOR-swizzled LDS (chunk c of row r at slot c ^ ((r>>1)&3)).
// Round-0 proven version: 128x128 tile, 761 TF, no spills, 0 bank conflicts.
// GEMM1 is launched as 3 column-chunk dispatches (768 blocks each = exactly
// 1 tail-free round at 3 blocks/CU) so the ~200us attn dispatch becomes the
// top rocprof row and we finally get its counters.
// ---------------------------------------------------------------------------
__device__ __forceinline__ void store_val(__bf16* p, float v) { *p = (__bf16)v; }
__device__ __forceinline__ void store_val(float* p, float v) { *p = v; }

template <typename OutT>
__global__ __launch_bounds__(256, 2) void gemm_bt_kernel(
    const __bf16* __restrict__ A, const __bf16* __restrict__ Bt,
    const float* __restrict__ bias, OutT* __restrict__ C,
    int M, int N, int K) {
  __shared__ __attribute__((aligned(16))) __bf16 sA[128 * 32];
  __shared__ __attribute__((aligned(16))) __bf16 sB[128 * 32];
  const int tid = threadIdx.x;
  const int wave = tid >> 6, lane = tid & 63;
  const int quad = lane >> 4, l15 = lane & 15;
  const int bm = blockIdx.y * 128, bn = blockIdx.x * 128;
  const int wr = (wave >> 1) * 64, wc = (wave & 1) * 64;

  const int srow = lane >> 2;
  const int scol = ((lane & 3) ^ ((lane >> 3) & 3)) * 8;  // swizzled source
  const __bf16* Ap = A + (long)(bm + wave * 32 + srow) * K + scol;
  const __bf16* Bp = Bt + (long)(bn + wave * 32 + srow) * K + scol;
  __bf16* sAw = &sA[wave * 32 * 32];
  __bf16* sBw = &sB[wave * 32 * 32];

  const int achunk = (quad ^ ((l15 >> 1) & 3)) * 8;  // swizzled frag read

  f32x4 acc[4][4] = {};

  for (int k0 = 0; k0 < K; k0 += 32) {
    __syncthreads();
    async16(Ap + k0, sAw);
    async16(Ap + k0 + (long)16 * K, sAw + 16 * 32);
    async16(Bp + k0, sBw);
    async16(Bp + k0 + (long)16 * K, sBw + 16 * 32);
    __syncthreads();
    bf16x8 af[4], bfr[4];
#pragma unroll
    for (int i = 0; i < 4; ++i)
      af[i] = *(const bf16x8*)&sA[(wr + i * 16 + l15) * 32 + achunk];
#pragma unroll
    for (int i = 0; i < 4; ++i)
      bfr[i] = *(const bf16x8*)&sB[(wc + i * 16 + l15) * 32 + achunk];
#pragma unroll
    for (int i = 0; i < 4; ++i)
#pragma unroll
      for (int j = 0; j < 4; ++j)
        acc[i][j] = __builtin_amdgcn_mfma_f32_16x16x32_bf16(af[i], bfr[j],
                                                            acc[i][j], 0, 0, 0);
  }

#pragma unroll
  for (int i = 0; i < 4; ++i) {
    int row0 = bm + wr + i * 16 + quad * 4;
#pragma unroll
    for (int j = 0; j < 4; ++j) {
      int col = bn + wc + j * 16 + l15;
      float bv = bias[col];
#pragma unroll
      for (int r = 0; r < 4; ++r)
        store_val(&C[(long)(row0 + r) * N + col], acc[i][j][r] + bv);
    }
  }
}

__global__ __launch_bounds__(256) void rmsnorm_kernel(
    __bf16* __restrict__ qkv, const float* __restrict__ qw,
    const float* __restrict__ kw) {
  const int r = blockIdx.x;
  const bool isQ = r < BS;
  const int row = isQ ? r : r - BS;
  __bf16* p = qkv + (long)row * N3 + (isQ ? 0 : DD);
  const float* w = isQ ? qw : kw;
  const float extra = isQ ? (0.0883883476483184f * 1.44269504088896f) : 1.0f;
  const int t = threadIdx.x;

  bf16x8 v = *(const bf16x8*)(p + t * 8);
  float f[8];
  float s = 0.f;
#pragma unroll
  for (int i = 0; i < 8; ++i) { f[i] = (float)v[i]; s += f[i] * f[i]; }
#pragma unroll
  for (int off = 32; off > 0; off >>= 1) s += __shfl_xor(s, off, 64);
  __shared__ float red[4];
  if ((t & 63) == 0) red[t >> 6] = s;
  __syncthreads();
  float tot = red[0] + red[1] + red[2] + red[3];
  float rs = rsqrtf(tot * (1.0f / (float)DD) + 1e-6f) * extra;
  const float4 w0 = *(const float4*)(w + t * 8);
  const float4 w1 = *(const float4*)(w + t * 8 + 4);
  bf16x8 o;
  o[0] = (__bf16)(f[0] * rs * w0.x); o[1] = (__bf16)(f[1] * rs * w0.y);
  o[2] = (__bf16)(f[2] * rs * w0.z); o[3] = (__bf16)(f[3] * rs * w0.w);
  o[4] = (__bf16)(f[4] * rs * w1.x); o[5] = (__bf16)(f[5] * rs * w1.y);
  o[6] = (__bf16)(f[6] * rs * w1.z); o[7] = (__bf16)(f[7] * rs * w1.w);
  *(bf16x8*)(p + t * 8) = o;
}

__global__ __launch_bounds__(256) void transpose_v_kernel(
    const __bf16* __restrict__ qkv, __bf16* __restrict__ vt) {
  __shared__ __bf16 t[32][33];
  const int bh = blockIdx.z, b = bh >> 4, h = bh & 15;
  const int s0 = blockIdx.x * 32, d0 = blockIdx.y * 32;
  const int tx = threadIdx.x & 31, ty = threadIdx.x >> 5;
#pragma unroll
  for (int i = 0; i < 4; ++i) {
    int s = s0 + ty + i * 8;
    t[ty + i * 8][tx] =
        qkv[(long)(b * SS + s) * N3 + 2 * DD + h * HD + d0 + tx];
  }
  __syncthreads();
#pragma unroll
  for (int i = 0; i < 4; ++i) {
    int d = d0 + ty + i * 8;
    vt[((long)bh * HD + d) * SS + s0 + tx] = t[tx][ty + i * 8];
  }
}

// ---------------------------------------------------------------------------
// Flash attention v5, causal. grid (S/128, B*H), 4 waves; wave owns 32 q-rows.
// Byte-exact round-0 version (setprio/reorder reverted: they cost ~10us).
// This round's goal is its first rocprof counter row, via the GEMM1 split.
// ---------------------------------------------------------------------------
__global__ __launch_bounds__(256, 2) void attn_kernel(
    const __bf16* __restrict__ qkv, const __bf16* __restrict__ vt,
    __bf16* __restrict__ O) {
  __shared__ __attribute__((aligned(16))) __bf16 sK[2][64 * 128];  // 32 KB
  __shared__ __attribute__((aligned(16))) __bf16 sV[2][128 * 64];  // 32 KB
  __shared__ __attribute__((aligned(16))) __bf16 sP[4][32 * 64];   // 16 KB

  const int qi = gridDim.x - 1 - blockIdx.x, bh = blockIdx.y;
  const int b = bh >> 4, h = bh & 15;
  const int tid = threadIdx.x, wave = tid >> 6, lane = tid & 63;
  const int quad = lane >> 4, l15 = lane & 15;
  const int sw3 = l15 & 7;

  const long rowQ0 = (long)(b * SS + qi * 128);   // block's first q row
  const int qrow0 = qi * 128 + wave * 32;         // wave's first q row (in S)
  const __bf16* kbase = qkv + (long)(b * SS) * N3 + DD + h * HD;
  const __bf16* vbase = vt + (long)bh * HD * SS;

  // Q fragments in registers: qf[mt][kk] for row-tile mt (rows +mt*16)
  bf16x8 qf[2][4];
#pragma unroll
  for (int mt = 0; mt < 2; ++mt) {
    const __bf16* qp =
        qkv + (rowQ0 + wave * 32 + mt * 16 + l15) * N3 + h * HD + quad * 8;
#pragma unroll
    for (int kk = 0; kk < 4; ++kk) qf[mt][kk] = *(const bf16x8*)(qp + kk * 32);
  }

  f32x4 o_acc[2][8] = {};
  float l_acc[2][4] = {};

  __bf16* sPw = &sP[wave][0];
  const int jn = 2 * qi + 2;  // K tiles 0 .. 2qi+1 (block-uniform)

  // ---- staging helper (wave-uniform LDS dst bases) ----
  auto stageKV = [&](int j, int buf) {
#pragma unroll
    for (int t = 0; t < 4; ++t) {  // K tile 64x128: inst covers 4 rows
      int rbase = wave * 16 + t * 4;            // wave-uniform
      int row = rbase + quad;
      const __bf16* src =
          kbase + (long)(j * 64 + row) * N3 + ((l15 ^ (row & 7)) * 8);
      async16(src, &sK[buf][rbase * 128]);
    }
#pragma unroll
    for (int t = 0; t < 4; ++t) {  // V^T tile 128x64: inst covers 8 rows
      int rbase = wave * 32 + t * 8;            // wave-uniform
      int row = rbase + (lane >> 3);
      const __bf16* src = vbase + (long)row * SS + j * 64 +
                          (((lane & 7) ^ (row & 7)) * 8);
      async16(src, &sV[buf][rbase * 64]);
    }
  };

  stageKV(0, 0);

  for (int j = 0; j < jn; ++j) {
    const int buf = j & 1;
    __syncthreads();                 // waits stage(j) (+ prev compute done)
    if (j + 1 < jn) stageKV(j + 1, buf ^ 1);  // prefetch, hidden by compute(j)

    // wave 0/1 rows are entirely above the diagonal for the final K tile
    const bool active = !((j == 2 * qi + 1) && (wave < 2));
    if (active) {
      const bool needMask =
          ((j == 2 * qi) && (wave < 2)) || ((j == 2 * qi + 1) && (wave >= 2));

      // ---- S = Q K^T : 16 bk reads feed 32 MFMAs ----
      f32x4 sacc[2][4];
#pragma unroll
      for (int nt = 0; nt < 4; ++nt) {
        sacc[0][nt] = (f32x4){0.f, 0.f, 0.f, 0.f};
        sacc[1][nt] = (f32x4){0.f, 0.f, 0.f, 0.f};
#pragma unroll
        for (int kk = 0; kk < 4; ++kk) {
          bf16x8 bk = *(const bf16x8*)
              &sK[buf][(nt * 16 + l15) * 128 + (((kk * 4 + quad) ^ sw3) * 8)];
          sacc[0][nt] = __builtin_amdgcn_mfma_f32_16x16x32_bf16(
              qf[0][kk], bk, sacc[0][nt], 0, 0, 0);
          sacc[1][nt] = __builtin_amdgcn_mfma_f32_16x16x32_bf16(
              qf[1][kk], bk, sacc[1][nt], 0, 0, 0);
        }
      }
      if (needMask) {
#pragma unroll
        for (int mt = 0; mt < 2; ++mt) {
          int rowg0 = qrow0 + mt * 16 + quad * 4;
#pragma unroll
          for (int nt = 0; nt < 4; ++nt) {
            int colg = j * 64 + nt * 16 + l15;
#pragma unroll
            for (int r = 0; r < 4; ++r)
              if (colg > rowg0 + r) sacc[mt][nt][r] = -1e30f;
          }
        }
      }
      // ---- p = exp2(s) -> sP (wave-private), accumulate l per lane ----
#pragma unroll
      for (int mt = 0; mt < 2; ++mt) {
#pragma unroll
        for (int nt = 0; nt < 4; ++nt) {
#pragma unroll
          for (int r = 0; r < 4; ++r) {
            float pv = exp2f(sacc[mt][nt][r]);
            l_acc[mt][r] += pv;
            int prow = mt * 16 + quad * 4 + r;
            int pcol = nt * 16 + l15;
            sPw[prow * 64 + (((pcol >> 3) ^ (prow & 7)) * 8) + (pcol & 7)] =
                (__bf16)pv;
          }
        }
      }
      // ---- O += P V : 4 ap + 16 bv reads feed 32 MFMAs ----
#pragma unroll
      for (int kk = 0; kk < 2; ++kk) {
        bf16x8 ap0 = *(const bf16x8*)
            &sPw[l15 * 64 + (((kk * 4 + quad) ^ sw3) * 8)];
        bf16x8 ap1 = *(const bf16x8*)
            &sPw[(16 + l15) * 64 + (((kk * 4 + quad) ^ sw3) * 8)];
#pragma unroll
        for (int dt = 0; dt < 8; ++dt) {
          bf16x8 bv = *(const bf16x8*)
              &sV[buf][(dt * 16 + l15) * 64 + (((kk * 4 + quad) ^ sw3) * 8)];
          o_acc[0][dt] = __builtin_amdgcn_mfma_f32_16x16x32_bf16(
              ap0, bv, o_acc[0][dt], 0, 0, 0);
          o_acc[1][dt] = __builtin_amdgcn_mfma_f32_16x16x32_bf16(
              ap1, bv, o_acc[1][dt], 0, 0, 0);
        }
      }
    }
  }

  // final l reduction across the 16 lanes of each quad-row, then write O
#pragma unroll
  for (int mt = 0; mt < 2; ++mt) {
    __bf16* obase = O + (rowQ0 + wave * 32 + mt * 16 + quad * 4) * DD + h * HD;
#pragma unroll
    for (int r = 0; r < 4; ++r) {
      float l = l_acc[mt][r];
#pragma unroll
      for (int off = 1; off < 16; off <<= 1) l += __shfl_xor(l, off, 64);
      float inv = 1.0f / l;
#pragma unroll
      for (int dt = 0; dt < 8; ++dt)
        obase[(long)r * DD + dt * 16 + l15] = (__bf16)(o_acc[mt][dt][r] * inv);
    }
  }
}

extern "C" void kernel_launch(void* const* d_in, const int* in_sizes, int n_in,
                              void* d_out, int out_size, void* d_ws,
                              size_t ws_size, hipStream_t stream) {
  const float* x      = (const float*)d_in[0];
  const float* w_qkv  = (const float*)d_in[1];
  const float* b_qkv  = (const float*)d_in[2];
  const float* q_ln_w = (const float*)d_in[3];
  const float* k_ln_w = (const float*)d_in[4];
  const float* w_out  = (const float*)d_in[5];
  const float* b_out  = (const float*)d_in[6];
  float* out = (float*)d_out;

  char* w = (char*)d_ws;
  __bf16* xb    = (__bf16*)(w);
  __bf16* wqkvT = (__bf16*)(w + 25165824L);
  __bf16* woutT = (__bf16*)(w + 50331648L);
  __bf16* qkvb  = (__bf16*)(w + 58720256L);
  __bf16* vtb   = (__bf16*)(w + 134217728L);
  __bf16* atto  = xb;

  cast_bf16_kernel<<<dim3(BS * DD / 2048), 256, 0, stream>>>(x, xb);
  transpose_cast_kernel<<<dim3(N3 / 32, DD / 32), 256, 0, stream>>>(
      w_qkv, wqkvT, DD, N3);
  transpose_cast_kernel<<<dim3(DD / 32, DD / 32), 256, 0, stream>>>(
      w_out, woutT, DD, DD);

  // GEMM1 split into 3 column-chunk dispatches (each 768 blocks = 1 clean
  // round at 3 blocks/CU) so attn becomes the top rocprof dispatch.
  for (int c = 0; c < 3; ++c) {
    gemm_bt_kernel<__bf16><<<dim3(DD / 128, BS / 128), 256, 0, stream>>>(
        xb, wqkvT + (long)c * DD * DD, b_qkv + c * DD, qkvb + c * DD,
        BS, N3, DD);
  }

  rmsnorm_kernel<<<dim3(2 * BS), 256, 0, stream>>>(qkvb, q_ln_w, k_ln_w);

  transpose_v_kernel<<<dim3(SS / 32, HD / 32, BB * HH), 256, 0, stream>>>(
      qkvb, vtb);

  attn_kernel<<<dim3(SS / 128, BB * HH), 256, 0, stream>>>(qkvb, vtb, atto);

  gemm_bt_kernel<float><<<dim3(DD / 128, BS / 128), 256, 0, stream>>>(
      atto, woutT, b_out, out, BS, DD, DD);
}

// Round 5
// 490.982 us; speedup vs baseline: 1.3008x; 1.0970x over previous
//
#include <hip/hip_runtime.h>
#include <stdint.h>

// Problem constants (B=4, S=1536, D=2048, H=16, hd=128)
#define BB 4
#define SS 1536
#define DD 2048
#define HH 16
#define HD 128
#define BS (BB * SS)        // 6144 rows
#define N3 (3 * DD)         // 6144

typedef __bf16 bf16x8 __attribute__((ext_vector_type(8)));
typedef float f32x4 __attribute__((ext_vector_type(4)));

__device__ __forceinline__ void async16(const void* g, void* lds) {
  __builtin_amdgcn_global_load_lds(
      (const __attribute__((address_space(1))) unsigned int*)g,
      (__attribute__((address_space(3))) unsigned int*)lds, 16, 0, 0);
}

__global__ __launch_bounds__(256) void cast_bf16_kernel(
    const float* __restrict__ in, __bf16* __restrict__ out) {
  long i = ((long)blockIdx.x * 256 + threadIdx.x) * 8;
  float4 a = *(const float4*)(in + i);
  float4 b = *(const float4*)(in + i + 4);
  bf16x8 o;
  o[0] = (__bf16)a.x; o[1] = (__bf16)a.y; o[2] = (__bf16)a.z; o[3] = (__bf16)a.w;
  o[4] = (__bf16)b.x; o[5] = (__bf16)b.y; o[6] = (__bf16)b.z; o[7] = (__bf16)b.w;
  *(bf16x8*)(out + i) = o;
}

__global__ __launch_bounds__(256) void transpose_cast_kernel(
    const float* __restrict__ in, __bf16* __restrict__ out, int R, int C) {
  __shared__ __bf16 t[32][33];
  int tx = threadIdx.x & 31, ty = threadIdx.x >> 5;  // 32 x 8
  long r0 = (long)blockIdx.y * 32, c0 = (long)blockIdx.x * 32;
#pragma unroll
  for (int i = 0; i < 4; ++i)
    t[ty + i * 8][tx] = (__bf16)in[(r0 + ty + i * 8) * C + c0 + tx];
  __syncthreads();
#pragma unroll
  for (int i = 0; i < 4; ++i)
    out[(c0 + ty + i * 8) * R + r0 + tx] = t[tx][ty + i * 8];
}

// ---------------------------------------------------------------------------
// GEMM with XOR-swizzled LDS (chunk c of row r at slot c ^ ((r>>1)&3)).
// Round-0 proven version: 128x128 tile, 761 TF, no spills, 0 bank conflicts.
// GEMM1 is launched as 3 column-chunk dispatches (768 blocks each = exactly
// 1 tail-free round at 3 blocks/CU) so attn stays visible in rocprof.
// ---------------------------------------------------------------------------
__device__ __forceinline__ void store_val(__bf16* p, float v) { *p = (__bf16)v; }
__device__ __forceinline__ void store_val(float* p, float v) { *p = v; }

template <typename OutT>
__global__ __launch_bounds__(256, 2) void gemm_bt_kernel(
    const __bf16* __restrict__ A, const __bf16* __restrict__ Bt,
    const float* __restrict__ bias, OutT* __restrict__ C,
    int M, int N, int K) {
  __shared__ __attribute__((aligned(16))) __bf16 sA[128 * 32];
  __shared__ __attribute__((aligned(16))) __bf16 sB[128 * 32];
  const int tid = threadIdx.x;
  const int wave = tid >> 6, lane = tid & 63;
  const int quad = lane >> 4, l15 = lane & 15;
  const int bm = blockIdx.y * 128, bn = blockIdx.x * 128;
  const int wr = (wave >> 1) * 64, wc = (wave & 1) * 64;

  const int srow = lane >> 2;
  const int scol = ((lane & 3) ^ ((lane >> 3) & 3)) * 8;  // swizzled source
  const __bf16* Ap = A + (long)(bm + wave * 32 + srow) * K + scol;
  const __bf16* Bp = Bt + (long)(bn + wave * 32 + srow) * K + scol;
  __bf16* sAw = &sA[wave * 32 * 32];
  __bf16* sBw = &sB[wave * 32 * 32];

  const int achunk = (quad ^ ((l15 >> 1) & 3)) * 8;  // swizzled frag read

  f32x4 acc[4][4] = {};

  for (int k0 = 0; k0 < K; k0 += 32) {
    __syncthreads();
    async16(Ap + k0, sAw);
    async16(Ap + k0 + (long)16 * K, sAw + 16 * 32);
    async16(Bp + k0, sBw);
    async16(Bp + k0 + (long)16 * K, sBw + 16 * 32);
    __syncthreads();
    bf16x8 af[4], bfr[4];
#pragma unroll
    for (int i = 0; i < 4; ++i)
      af[i] = *(const bf16x8*)&sA[(wr + i * 16 + l15) * 32 + achunk];
#pragma unroll
    for (int i = 0; i < 4; ++i)
      bfr[i] = *(const bf16x8*)&sB[(wc + i * 16 + l15) * 32 + achunk];
#pragma unroll
    for (int i = 0; i < 4; ++i)
#pragma unroll
      for (int j = 0; j < 4; ++j)
        acc[i][j] = __builtin_amdgcn_mfma_f32_16x16x32_bf16(af[i], bfr[j],
                                                            acc[i][j], 0, 0, 0);
  }

#pragma unroll
  for (int i = 0; i < 4; ++i) {
    int row0 = bm + wr + i * 16 + quad * 4;
#pragma unroll
    for (int j = 0; j < 4; ++j) {
      int col = bn + wc + j * 16 + l15;
      float bv = bias[col];
#pragma unroll
      for (int r = 0; r < 4; ++r)
        store_val(&C[(long)(row0 + r) * N + col], acc[i][j][r] + bv);
    }
  }
}

__global__ __launch_bounds__(256) void rmsnorm_kernel(
    __bf16* __restrict__ qkv, const float* __restrict__ qw,
    const float* __restrict__ kw) {
  const int r = blockIdx.x;
  const bool isQ = r < BS;
  const int row = isQ ? r : r - BS;
  __bf16* p = qkv + (long)row * N3 + (isQ ? 0 : DD);
  const float* w = isQ ? qw : kw;
  const float extra = isQ ? (0.0883883476483184f * 1.44269504088896f) : 1.0f;
  const int t = threadIdx.x;

  bf16x8 v = *(const bf16x8*)(p + t * 8);
  float f[8];
  float s = 0.f;
#pragma unroll
  for (int i = 0; i < 8; ++i) { f[i] = (float)v[i]; s += f[i] * f[i]; }
#pragma unroll
  for (int off = 32; off > 0; off >>= 1) s += __shfl_xor(s, off, 64);
  __shared__ float red[4];
  if ((t & 63) == 0) red[t >> 6] = s;
  __syncthreads();
  float tot = red[0] + red[1] + red[2] + red[3];
  float rs = rsqrtf(tot * (1.0f / (float)DD) + 1e-6f) * extra;
  const float4 w0 = *(const float4*)(w + t * 8);
  const float4 w1 = *(const float4*)(w + t * 8 + 4);
  bf16x8 o;
  o[0] = (__bf16)(f[0] * rs * w0.x); o[1] = (__bf16)(f[1] * rs * w0.y);
  o[2] = (__bf16)(f[2] * rs * w0.z); o[3] = (__bf16)(f[3] * rs * w0.w);
  o[4] = (__bf16)(f[4] * rs * w1.x); o[5] = (__bf16)(f[5] * rs * w1.y);
  o[6] = (__bf16)(f[6] * rs * w1.z); o[7] = (__bf16)(f[7] * rs * w1.w);
  *(bf16x8*)(p + t * 8) = o;
}

__global__ __launch_bounds__(256) void transpose_v_kernel(
    const __bf16* __restrict__ qkv, __bf16* __restrict__ vt) {
  __shared__ __bf16 t[32][33];
  const int bh = blockIdx.z, b = bh >> 4, h = bh & 15;
  const int s0 = blockIdx.x * 32, d0 = blockIdx.y * 32;
  const int tx = threadIdx.x & 31, ty = threadIdx.x >> 5;
#pragma unroll
  for (int i = 0; i < 4; ++i) {
    int s = s0 + ty + i * 8;
    t[ty + i * 8][tx] =
        qkv[(long)(b * SS + s) * N3 + 2 * DD + h * HD + d0 + tx];
  }
  __syncthreads();
#pragma unroll
  for (int i = 0; i < 4; ++i) {
    int d = d0 + ty + i * 8;
    vt[((long)bh * HD + d) * SS + s0 + tx] = t[tx][ty + i * 8];
  }
}

// ---------------------------------------------------------------------------
// Flash attention v5, causal. 1-D grid of 768 persistent-order blocks with
// LPT (largest-processing-time-first) work mapping:
//   rank r -> qi = 11 - (r>>6)  (all 64 qi=11 blocks dispatch FIRST),
//             bh = r & 63.
// Round-4 counters showed OccupancyPercent 10.6% (3.4 waves/CU resident vs 8
// supported): the old (12,64) grid dispatched ~21 of the 24-iteration qi=11
// blocks in the LAST 256 ranks -> they ran nearly alone at the end. LPT kills
// that tail. Side benefit: blocks sharing a bh are 64 apart in rank and
// 64%8==0, so all 12 land on the same XCD -> K/V L2 locality.
// Kernel body otherwise byte-identical to the round-0 proven version.
// ---------------------------------------------------------------------------
__global__ __launch_bounds__(256, 2) void attn_kernel(
    const __bf16* __restrict__ qkv, const __bf16* __restrict__ vt,
    __bf16* __restrict__ O) {
  __shared__ __attribute__((aligned(16))) __bf16 sK[2][64 * 128];  // 32 KB
  __shared__ __attribute__((aligned(16))) __bf16 sV[2][128 * 64];  // 32 KB
  __shared__ __attribute__((aligned(16))) __bf16 sP[4][32 * 64];   // 16 KB

  const int rank = blockIdx.x;
  const int qi = 11 - (rank >> 6);   // LPT: big blocks first
  const int bh = rank & 63;
  const int b = bh >> 4, h = bh & 15;
  const int tid = threadIdx.x, wave = tid >> 6, lane = tid & 63;
  const int quad = lane >> 4, l15 = lane & 15;
  const int sw3 = l15 & 7;

  const long rowQ0 = (long)(b * SS + qi * 128);   // block's first q row
  const int qrow0 = qi * 128 + wave * 32;         // wave's first q row (in S)
  const __bf16* kbase = qkv + (long)(b * SS) * N3 + DD + h * HD;
  const __bf16* vbase = vt + (long)bh * HD * SS;

  // Q fragments in registers: qf[mt][kk] for row-tile mt (rows +mt*16)
  bf16x8 qf[2][4];
#pragma unroll
  for (int mt = 0; mt < 2; ++mt) {
    const __bf16* qp =
        qkv + (rowQ0 + wave * 32 + mt * 16 + l15) * N3 + h * HD + quad * 8;
#pragma unroll
    for (int kk = 0; kk < 4; ++kk) qf[mt][kk] = *(const bf16x8*)(qp + kk * 32);
  }

  f32x4 o_acc[2][8] = {};
  float l_acc[2][4] = {};

  __bf16* sPw = &sP[wave][0];
  const int jn = 2 * qi + 2;  // K tiles 0 .. 2qi+1 (block-uniform)

  // ---- staging helper (wave-uniform LDS dst bases) ----
  auto stageKV = [&](int j, int buf) {
#pragma unroll
    for (int t = 0; t < 4; ++t) {  // K tile 64x128: inst covers 4 rows
      int rbase = wave * 16 + t * 4;            // wave-uniform
      int row = rbase + quad;
      const __bf16* src =
          kbase + (long)(j * 64 + row) * N3 + ((l15 ^ (row & 7)) * 8);
      async16(src, &sK[buf][rbase * 128]);
    }
#pragma unroll
    for (int t = 0; t < 4; ++t) {  // V^T tile 128x64: inst covers 8 rows
      int rbase = wave * 32 + t * 8;            // wave-uniform
      int row = rbase + (lane >> 3);
      const __bf16* src = vbase + (long)row * SS + j * 64 +
                          (((lane & 7) ^ (row & 7)) * 8);
      async16(src, &sV[buf][rbase * 64]);
    }
  };

  stageKV(0, 0);

  for (int j = 0; j < jn; ++j) {
    const int buf = j & 1;
    __syncthreads();                 // waits stage(j) (+ prev compute done)
    if (j + 1 < jn) stageKV(j + 1, buf ^ 1);  // prefetch, hidden by compute(j)

    // wave 0/1 rows are entirely above the diagonal for the final K tile
    const bool active = !((j == 2 * qi + 1) && (wave < 2));
    if (active) {
      const bool needMask =
          ((j == 2 * qi) && (wave < 2)) || ((j == 2 * qi + 1) && (wave >= 2));

      // ---- S = Q K^T : 16 bk reads feed 32 MFMAs ----
      f32x4 sacc[2][4];
#pragma unroll
      for (int nt = 0; nt < 4; ++nt) {
        sacc[0][nt] = (f32x4){0.f, 0.f, 0.f, 0.f};
        sacc[1][nt] = (f32x4){0.f, 0.f, 0.f, 0.f};
#pragma unroll
        for (int kk = 0; kk < 4; ++kk) {
          bf16x8 bk = *(const bf16x8*)
              &sK[buf][(nt * 16 + l15) * 128 + (((kk * 4 + quad) ^ sw3) * 8)];
          sacc[0][nt] = __builtin_amdgcn_mfma_f32_16x16x32_bf16(
              qf[0][kk], bk, sacc[0][nt], 0, 0, 0);
          sacc[1][nt] = __builtin_amdgcn_mfma_f32_16x16x32_bf16(
              qf[1][kk], bk, sacc[1][nt], 0, 0, 0);
        }
      }
      if (needMask) {
#pragma unroll
        for (int mt = 0; mt < 2; ++mt) {
          int rowg0 = qrow0 + mt * 16 + quad * 4;
#pragma unroll
          for (int nt = 0; nt < 4; ++nt) {
            int colg = j * 64 + nt * 16 + l15;
#pragma unroll
            for (int r = 0; r < 4; ++r)
              if (colg > rowg0 + r) sacc[mt][nt][r] = -1e30f;
          }
        }
      }
      // ---- p = exp2(s) -> sP (wave-private), accumulate l per lane ----
#pragma unroll
      for (int mt = 0; mt < 2; ++mt) {
#pragma unroll
        for (int nt = 0; nt < 4; ++nt) {
#pragma unroll
          for (int r = 0; r < 4; ++r) {
            float pv = exp2f(sacc[mt][nt][r]);
            l_acc[mt][r] += pv;
            int prow = mt * 16 + quad * 4 + r;
            int pcol = nt * 16 + l15;
            sPw[prow * 64 + (((pcol >> 3) ^ (prow & 7)) * 8) + (pcol & 7)] =
                (__bf16)pv;
          }
        }
      }
      // ---- O += P V : 4 ap + 16 bv reads feed 32 MFMAs ----
#pragma unroll
      for (int kk = 0; kk < 2; ++kk) {
        bf16x8 ap0 = *(const bf16x8*)
            &sPw[l15 * 64 + (((kk * 4 + quad) ^ sw3) * 8)];
        bf16x8 ap1 = *(const bf16x8*)
            &sPw[(16 + l15) * 64 + (((kk * 4 + quad) ^ sw3) * 8)];
#pragma unroll
        for (int dt = 0; dt < 8; ++dt) {
          bf16x8 bv = *(const bf16x8*)
              &sV[buf][(dt * 16 + l15) * 64 + (((kk * 4 + quad) ^ sw3) * 8)];
          o_acc[0][dt] = __builtin_amdgcn_mfma_f32_16x16x32_bf16(
              ap0, bv, o_acc[0][dt], 0, 0, 0);
          o_acc[1][dt] = __builtin_amdgcn_mfma_f32_16x16x32_bf16(
              ap1, bv, o_acc[1][dt], 0, 0, 0);
        }
      }
    }
  }

  // final l reduction across the 16 lanes of each quad-row, then write O
#pragma unroll
  for (int mt = 0; mt < 2; ++mt) {
    __bf16* obase = O + (rowQ0 + wave * 32 + mt * 16 + quad * 4) * DD + h * HD;
#pragma unroll
    for (int r = 0; r < 4; ++r) {
      float l = l_acc[mt][r];
#pragma unroll
      for (int off = 1; off < 16; off <<= 1) l += __shfl_xor(l, off, 64);
      float inv = 1.0f / l;
#pragma unroll
      for (int dt = 0; dt < 8; ++dt)
        obase[(long)r * DD + dt * 16 + l15] = (__bf16)(o_acc[mt][dt][r] * inv);
    }
  }
}

extern "C" void kernel_launch(void* const* d_in, const int* in_sizes, int n_in,
                              void* d_out, int out_size, void* d_ws,
                              size_t ws_size, hipStream_t stream) {
  const float* x      = (const float*)d_in[0];
  const float* w_qkv  = (const float*)d_in[1];
  const float* b_qkv  = (const float*)d_in[2];
  const float* q_ln_w = (const float*)d_in[3];
  const float* k_ln_w = (const float*)d_in[4];
  const float* w_out  = (const float*)d_in[5];
  const float* b_out  = (const float*)d_in[6];
  float* out = (float*)d_out;

  char* w = (char*)d_ws;
  __bf16* xb    = (__bf16*)(w);
  __bf16* wqkvT = (__bf16*)(w + 25165824L);
  __bf16* woutT = (__bf16*)(w + 50331648L);
  __bf16* qkvb  = (__bf16*)(w + 58720256L);
  __bf16* vtb   = (__bf16*)(w + 134217728L);
  __bf16* atto  = xb;

  cast_bf16_kernel<<<dim3(BS * DD / 2048), 256, 0, stream>>>(x, xb);
  transpose_cast_kernel<<<dim3(N3 / 32, DD / 32), 256, 0, stream>>>(
      w_qkv, wqkvT, DD, N3);
  transpose_cast_kernel<<<dim3(DD / 32, DD / 32), 256, 0, stream>>>(
      w_out, woutT, DD, DD);

  // GEMM1 split into 3 column-chunk dispatches (each 768 blocks = 1 clean
  // round at 3 blocks/CU) so attn stays the top rocprof dispatch.
  for (int c = 0; c < 3; ++c) {
    gemm_bt_kernel<__bf16><<<dim3(DD / 128, BS / 128), 256, 0, stream>>>(
        xb, wqkvT + (long)c * DD * DD, b_qkv + c * DD, qkvb + c * DD,
        BS, N3, DD);
  }

  rmsnorm_kernel<<<dim3(2 * BS), 256, 0, stream>>>(qkvb, q_ln_w, k_ln_w);

  transpose_v_kernel<<<dim3(SS / 32, HD / 32, BB * HH), 256, 0, stream>>>(
      qkvb, vtb);

  attn_kernel<<<dim3(SS / 128 * BB * HH), 256, 0, stream>>>(qkvb, vtb, atto);

  gemm_bt_kernel<float><<<dim3(DD / 128, BS / 128), 256, 0, stream>>>(
      atto, woutT, b_out, out, BS, DD, DD);
}